// Round 11
// baseline (1095.916 us; speedup 1.0000x reference)
//
#include <hip/hip_runtime.h>
#include <hip/hip_fp16.h>

// MoE: B=4 S=2048 D=1024 E=8 K=2 H=4096. T=8192 tokens, 16384 assignments.
// R11: codegen fixes vs proven m201 template (FFN1 stuck at 34% MfmaUtil,
// 14.1k cyc/iter vs template's ~2k for identical geometry):
//  (1) BAR: sched_barrier(0) pins -> memory-only fences (asm "" memory)
//      around s_barrier. MFMA/VALU now free to interleave across phases;
//      LDS ordering (race safety) preserved.
//  (2) QUAD: k-half outer, (m,n) inner -> consecutive MFMAs independent
//      (was: every 2nd MFMA acc-dependent = latency bubble).
// Everything else (R8 waits, R6 panel-affinity, R10 split-K partials) kept.

#define T_TOK 8192
#define D_IN  1024
#define E_EXP 8
#define H_HID 4096
#define NSLOT (T_TOK * 2)
#define NSLOT_PAD (NSLOT + 256)
#define KSPLIT 4

typedef _Float16 f16;
typedef __attribute__((ext_vector_type(8))) _Float16 f16x8;
typedef __attribute__((ext_vector_type(4))) _Float16 f16x4;
typedef __attribute__((ext_vector_type(4))) float f32x4;

__device__ __forceinline__ void gload_lds16(const void* g, void* l) {
  __builtin_amdgcn_global_load_lds(
      (const __attribute__((address_space(1))) unsigned int*)g,
      (__attribute__((address_space(3))) unsigned int*)l, 16, 0, 0);
}

// ---------------- weight transpose ----------------
// src [e][R][C] f32 -> dst f16 [e][*][R]; MAP0: row=c; MAP1: gate interleave;
// MAP2: up interleave (rows 32j+16.. for source col 16j..).
template<int MAP>
__global__ __launch_bounds__(256) void transpose_cvt_kernel(
    const float* __restrict__ src, f16* __restrict__ dst, int R, int C,
    size_t dstride) {
  __shared__ float tile[32][33];
  int b = blockIdx.z;
  const float* s = src + (size_t)b * R * C;
  f16* d = dst + (size_t)b * dstride;
  int c0 = blockIdx.x * 32, r0 = blockIdx.y * 32;
  int tr = threadIdx.x >> 3;
  int tc4 = (threadIdx.x & 7) * 4;
  float4 v = *(const float4*)(s + (size_t)(r0 + tr) * C + c0 + tc4);
  tile[tr][tc4 + 0] = v.x;
  tile[tr][tc4 + 1] = v.y;
  tile[tr][tc4 + 2] = v.z;
  tile[tr][tc4 + 3] = v.w;
  __syncthreads();
  int c = c0 + tr;
  int ro = (MAP == 0) ? c : (((c >> 4) << 5) + ((MAP == 2) ? 16 : 0) + (c & 15));
  f16x4 o = {(f16)tile[tc4 + 0][tr], (f16)tile[tc4 + 1][tr],
             (f16)tile[tc4 + 2][tr], (f16)tile[tc4 + 3][tr]};
  *(f16x4*)(d + (size_t)ro * R + r0 + tc4) = o;
}

// ---------------- router (+ x -> f16 conversion fused) ----------------

__global__ __launch_bounds__(256) void router_kernel(
    const float* __restrict__ x, const float* __restrict__ Wr,
    const float* __restrict__ br, int* __restrict__ eidx,
    float2* __restrict__ pval, int* __restrict__ counts,
    f16* __restrict__ xb) {
  int lane = threadIdx.x & 63, wid = threadIdx.x >> 6;
  int t = blockIdx.x * 4 + wid;
  const float* xr = x + (size_t)t * D_IN;
  float s[8] = {0.f, 0.f, 0.f, 0.f, 0.f, 0.f, 0.f, 0.f};
  int dbase = lane * 16;
#pragma unroll
  for (int i = 0; i < 4; ++i) {
    float4 xv = *(const float4*)(xr + dbase + i * 4);
    f16x4 xo = {(f16)xv.x, (f16)xv.y, (f16)xv.z, (f16)xv.w};
    *(f16x4*)(xb + (size_t)t * D_IN + dbase + i * 4) = xo;
    const float xs[4] = {xv.x, xv.y, xv.z, xv.w};
#pragma unroll
    for (int j = 0; j < 4; ++j) {
      const float* wr = Wr + (size_t)(dbase + i * 4 + j) * E_EXP;
      float4 w0 = *(const float4*)wr;
      float4 w1 = *(const float4*)(wr + 4);
      float xvj = xs[j];
      s[0] += xvj * w0.x; s[1] += xvj * w0.y; s[2] += xvj * w0.z; s[3] += xvj * w0.w;
      s[4] += xvj * w1.x; s[5] += xvj * w1.y; s[6] += xvj * w1.z; s[7] += xvj * w1.w;
    }
  }
#pragma unroll
  for (int off = 32; off; off >>= 1)
#pragma unroll
    for (int e = 0; e < 8; ++e) s[e] += __shfl_xor(s[e], off);
  if (lane == 0) {
    float v[8];
#pragma unroll
    for (int e = 0; e < 8; ++e) v[e] = s[e] + br[e];
    int i0 = 0; float v0 = v[0];
#pragma unroll
    for (int e = 1; e < 8; ++e) if (v[e] > v0) { v0 = v[e]; i0 = e; }
    int i1 = -1; float v1 = -1e30f;
#pragma unroll
    for (int e = 0; e < 8; ++e)
      if (e != i0 && v[e] > v1) { v1 = v[e]; i1 = e; }
    float ed = __expf(v1 - v0);
    float inv = 1.f / (1.f + ed);
    eidx[t] = i0 | (i1 << 8);
    pval[t] = make_float2(inv, ed * inv);
    atomicAdd(&counts[i0], 1);
    atomicAdd(&counts[i1], 1);
  }
}

__global__ void scan_kernel(const int* __restrict__ counts, int* __restrict__ offsets) {
  if (threadIdx.x == 0) {
    int acc = 0;
#pragma unroll
    for (int e = 0; e < E_EXP; ++e) { offsets[e] = acc; acc += counts[e]; }
    offsets[E_EXP] = acc;
  }
}

__global__ __launch_bounds__(256) void scatter_kernel(
    const int* __restrict__ eidx, const float2* __restrict__ pval,
    const int* __restrict__ offsets, int* __restrict__ cursors,
    int* __restrict__ perm, float* __restrict__ gatew, int2* __restrict__ slotAB) {
  int t = blockIdx.x * 256 + threadIdx.x;
  if (t >= T_TOK) return;
  int ei = eidx[t];
  float2 p = pval[t];
  int e0 = ei & 0xff, e1 = (ei >> 8) & 0xff;
  int s0 = offsets[e0] + atomicAdd(&cursors[e0], 1);
  perm[s0] = t; gatew[s0] = p.x;
  int s1 = offsets[e1] + atomicAdd(&cursors[e1], 1);
  perm[s1] = t; gatew[s1] = p.y;
  slotAB[t] = make_int2(s0, s1);
}

// ---------------- 8-phase 256x256 grouped GEMM ----------------
// 512 thr = 8 waves (2M x 4N). LDS 128KB: buf{0,1} x (A[256][64] | B[256][64]),
// rows 128B, 16B chunk c of row r at physical c^(r&7).
// MODE0 (FFN1): grid 8192; panel=(g&7)+8*(g>>8); e=p>>5, nt=p&31; K=1024.
// MODE1 (FFN2): grid 4096; sp=(g&7)+8*(g>>8); e=sp>>4, nt=(sp>>2)&3, kc=sp&3.
// Waits (R8): vmcnt(6)@prologue, vmcnt(4)@P4-end, vmcnt(6)@P8-end,
// all placed before the barrier that precedes the dependent reads.

// memory-only compiler fence: boxes LDS/global ops between barriers
// (race safety) without pinning MFMA/VALU scheduling (m141 lesson).
#define BAR do {                              \
  asm volatile("" ::: "memory");              \
  __builtin_amdgcn_s_barrier();               \
  asm volatile("" ::: "memory");              \
} while (0)
#define VMCNT(N) asm volatile("s_waitcnt vmcnt(" #N ")" ::: "memory")

#define STAGE_(B, ISB, H, KT, BASE) do {                                   \
  char* d_ = smem + (B)*65536 + (ISB)*32768 + (H)*16384 + wid*1024;        \
  gload_lds16(BASE[(H)*2+0] + (size_t)(KT)*64, d_);                        \
  gload_lds16(BASE[(H)*2+1] + (size_t)(KT)*64, d_ + 8192);                 \
} while (0)

#define LDA_(B, Q)                                                          \
  _Pragma("unroll")                                                         \
  for (int m_ = 0; m_ < 4; ++m_) {                                          \
    fa[m_][0] = *(const f16x8*)(smem + (B)*65536 + aoff + ((Q)*4+m_)*2048 + offk0); \
    fa[m_][1] = *(const f16x8*)(smem + (B)*65536 + aoff + ((Q)*4+m_)*2048 + offk1); \
  }

#define LDB_(FB, B, RH)                                                     \
  _Pragma("unroll")                                                         \
  for (int n_ = 0; n_ < 2; ++n_) {                                          \
    FB[n_][0] = *(const f16x8*)(smem + (B)*65536 + 32768 + boff + ((RH)*2+n_)*2048 + offk0); \
    FB[n_][1] = *(const f16x8*)(smem + (B)*65536 + 32768 + boff + ((RH)*2+n_)*2048 + offk1); \
  }

// k-half OUTER: consecutive MFMAs hit different acc -> no dep bubbles.
#define QUAD_(Q, RH, FB)                                                    \
  __builtin_amdgcn_s_setprio(1);                                            \
  _Pragma("unroll")                                                         \
  for (int k_ = 0; k_ < 2; ++k_)                                            \
    _Pragma("unroll")                                                       \
    for (int m_ = 0; m_ < 4; ++m_)                                          \
      _Pragma("unroll")                                                     \
      for (int n_ = 0; n_ < 2; ++n_)                                        \
        acc[(Q)*4+m_][(RH)*2+n_] = __builtin_amdgcn_mfma_f32_16x16x32_f16(  \
            fa[m_][k_], FB[n_][k_], acc[(Q)*4+m_][(RH)*2+n_], 0, 0, 0);     \
  __builtin_amdgcn_s_setprio(0);

template<int MODE>
__global__ __launch_bounds__(512, 2) void ffn_8ph_kernel(
    const f16* __restrict__ Asrc, const f16* __restrict__ Bsrc,
    const float* __restrict__ bias0, const float* __restrict__ bias1,
    const int* __restrict__ offsets, const int* __restrict__ perm,
    const float* __restrict__ gatew, f16* __restrict__ dst) {
  constexpr int KD = MODE ? H_HID : D_IN;        // full K dim of operands
  constexpr int BROWS = MODE ? D_IN : 2 * H_HID; // B rows per expert
  constexpr int NT = 16;                         // K-tiles per block

  __shared__ __align__(16) char smem[131072];

  // XCD-panel-affinity decode (all mt of one panel on one XCD).
  int g = blockIdx.x;
  int xcd = g & 7;
  int mt = (g >> 3) & 31;
  int e, nt, kc;
  if constexpr (MODE == 0) {
    int panel = xcd + 8 * (g >> 8);   // [0,256)
    e = panel >> 5; nt = panel & 31; kc = 0;
  } else {
    int sp = xcd + 8 * (g >> 8);      // [0,128)
    e = sp >> 4; nt = (sp >> 2) & 3; kc = sp & 3;
  }

  int off = offsets[e];
  int cnt = offsets[e + 1] - off;
  if (mt * 256 >= cnt) return;

  int tid = threadIdx.x, lane = tid & 63, wid = tid >> 6;
  int wm = wid >> 2, wn = wid & 3;
  int l15 = lane & 15, lc0 = lane >> 4, s7 = l15 & 7;
  int aoff = (wm * 128 + l15) * 128;
  int boff = (wn * 64 + l15) * 128;
  int offk0 = ((lc0) ^ s7) * 16;
  int offk1 = ((lc0 + 4) ^ s7) * 16;

  // chunk geometry shared by A/B staging pointers
  int rowh_[2], lc_[2];
#pragma unroll
  for (int i = 0; i < 2; ++i) {
    int chunk = (i * 8 + wid) * 64 + lane;
    rowh_[i] = chunk >> 3;
    lc_[i] = (chunk & 7) ^ (rowh_[i] & 7);
  }

  const f16 *aB[4], *bB[4];
#pragma unroll
  for (int h = 0; h < 2; ++h)
#pragma unroll
    for (int i = 0; i < 2; ++i) {
      int absrow = h * 128 + rowh_[i];
      bB[h * 2 + i] = Bsrc + ((size_t)e * BROWS + nt * 256 + absrow) * KD +
                      kc * 1024 + lc_[i] * 8;
      int slot = off + min(mt * 256 + absrow, cnt - 1);
      if constexpr (MODE == 0)
        aB[h * 2 + i] = Asrc + (size_t)perm[slot] * KD + lc_[i] * 8;
      else
        aB[h * 2 + i] = Asrc + (size_t)slot * KD + kc * 1024 + lc_[i] * 8;
    }

  // hoisted biases (MODE1: bias only in the kc==0 partial)
  float bv0[4], bv1[2];
  if constexpr (MODE == 0) {
#pragma unroll
    for (int p = 0; p < 2; ++p) {
      int h = nt * 128 + wn * 32 + p * 16 + l15;
      bv0[p] = bias0[e * H_HID + h];
      bv1[p] = bias1[e * H_HID + h];
    }
  } else {
#pragma unroll
    for (int n = 0; n < 4; ++n)
      bv0[n] = (kc == 0)
                   ? bias0[e * D_IN + nt * 256 + wn * 64 + n * 16 + l15]
                   : 0.f;
  }

  f32x4 acc[8][4] = {};
  f16x8 fa[4][2], fb01[2][2], fb23[2][2];

  // prologue: buf0.B, buf0.A (t0); buf1.B (t1); buf1.A-H0 (t1) — 14 loads.
  STAGE_(0, 1, 0, 0, bB); STAGE_(0, 1, 1, 0, bB);
  STAGE_(0, 0, 0, 0, aB); STAGE_(0, 0, 1, 0, aB);
  STAGE_(1, 1, 0, 1, bB); STAGE_(1, 1, 1, 1, bB);
  STAGE_(1, 0, 0, 1, aB);
  VMCNT(6);   // buf0 complete; buf1.B + buf1.A-H0 (6) still in flight
  BAR;

  for (int it = 0; it < NT / 2; ++it) {
    int b_ = 2 * it + 1;
    int a2 = min(2 * it + 2, NT - 1);
    int b2 = min(2 * it + 3, NT - 1);
    // P1: read buf0 (ready); finish buf1.A (H1, odd tile)
    LDA_(0, 0); LDB_(fb01, 0, 0); STAGE_(1, 0, 1, b_, aB);
    BAR; QUAD_(0, 0, fb01); BAR;
    // P2
    LDB_(fb23, 0, 1);
    BAR; QUAD_(0, 1, fb23); BAR;
    // P3: buf0.B free -> stage B(a+2)
    LDA_(0, 1); STAGE_(0, 1, 0, a2, bB);
    BAR; QUAD_(1, 0, fb01); BAR;
    // P4: drain so buf1 is ready for P5 reads
    STAGE_(0, 1, 1, a2, bB);
    BAR; QUAD_(1, 1, fb23);
    VMCNT(4);   // leaves P3+P4 (buf0.B) in flight
    BAR;
    // P5: read buf1 (ready); buf0.A free -> stage A(a+2)
    LDA_(1, 0); LDB_(fb01, 1, 0); STAGE_(0, 0, 0, a2, aB);
    BAR; QUAD_(0, 0, fb01); BAR;
    // P6
    LDB_(fb23, 1, 1); STAGE_(0, 0, 1, a2, aB);
    BAR; QUAD_(0, 1, fb23); BAR;
    // P7: buf1.B free -> stage B(b+2)
    LDA_(1, 1); STAGE_(1, 1, 0, b2, bB);
    BAR; QUAD_(1, 0, fb01); BAR;
    // P8: drain so buf0 is ready for next P1 reads
    STAGE_(1, 1, 1, b2, bB); STAGE_(1, 0, 0, b2, aB);
    BAR; QUAD_(1, 1, fb23);
    VMCNT(6);   // leaves P7+P8 (buf1.B + buf1.A-H0) in flight
    BAR;
  }

  int c0_ = lc0 * 4;
  if constexpr (MODE == 0) {
#pragma unroll
    for (int p = 0; p < 2; ++p) {
      int h = nt * 128 + wn * 32 + p * 16 + l15;
#pragma unroll
      for (int m = 0; m < 8; ++m) {
        int lbase = mt * 256 + wm * 128 + m * 16 + c0_;
#pragma unroll
        for (int r = 0; r < 4; ++r) {
          if (lbase + r < cnt) {
            float gv = acc[m][2 * p][r] + bv0[p];
            float uv = acc[m][2 * p + 1][r] + bv1[p];
            __builtin_nontemporal_store(
                (f16)((gv / (1.f + __expf(-gv))) * uv),
                &dst[(size_t)(off + lbase + r) * H_HID + h]);
          }
        }
      }
    }
  } else {
    // partial buffer kc (disjoint, no atomics)
    f16* dstP = dst + (size_t)kc * NSLOT_PAD * D_IN;
#pragma unroll
    for (int n = 0; n < 4; ++n) {
      int col = nt * 256 + wn * 64 + n * 16 + l15;
#pragma unroll
      for (int m = 0; m < 8; ++m) {
        int lbase = mt * 256 + wm * 128 + m * 16 + c0_;
#pragma unroll
        for (int r = 0; r < 4; ++r) {
          if (lbase + r < cnt) {
            int slot = off + lbase + r;
            __builtin_nontemporal_store(
                (f16)(gatew[slot] * (acc[m][n][r] + bv0[n])),
                &dstP[(size_t)slot * D_IN + col]);
          }
        }
      }
    }
  }
}

// ------- combine: out[t] = sum over s in {s0,s1}, kc in [0,4) of partial -------
__global__ __launch_bounds__(256) void combine_kernel(
    const f16* __restrict__ ypart, const int2* __restrict__ slotAB,
    float* __restrict__ out) {
  int i = blockIdx.x * 256 + threadIdx.x;
  int t = i >> 7;
  int c8 = i & 127;
  int2 s = slotAB[t];
  float sum[8] = {0.f, 0.f, 0.f, 0.f, 0.f, 0.f, 0.f, 0.f};
#pragma unroll
  for (int kc = 0; kc < KSPLIT; ++kc) {
    const f16* base = ypart + (size_t)kc * NSLOT_PAD * D_IN + c8 * 8;
    f16x8 y0 = *(const f16x8*)(base + (size_t)s.x * D_IN);
    f16x8 y1 = *(const f16x8*)(base + (size_t)s.y * D_IN);
#pragma unroll
    for (int j = 0; j < 8; ++j) sum[j] += (float)y0[j] + (float)y1[j];
  }
  float* o = out + (size_t)t * D_IN + c8 * 8;
  f32x4 o0 = {sum[0], sum[1], sum[2], sum[3]};
  f32x4 o1 = {sum[4], sum[5], sum[6], sum[7]};
  __builtin_nontemporal_store(o0, (f32x4*)o);
  __builtin_nontemporal_store(o1, (f32x4*)(o + 4));
}

// ---------------- launch ----------------

extern "C" void kernel_launch(void* const* d_in, const int* in_sizes, int n_in,
                              void* d_out, int out_size, void* d_ws, size_t ws_size,
                              hipStream_t stream) {
  const float* x  = (const float*)d_in[0];
  const float* Wr = (const float*)d_in[1];
  const float* br = (const float*)d_in[2];
  const float* Wg = (const float*)d_in[3];
  const float* bg = (const float*)d_in[4];
  const float* Wu = (const float*)d_in[5];
  const float* bu = (const float*)d_in[6];
  const float* Wd = (const float*)d_in[7];
  const float* bd = (const float*)d_in[8];
  float* out = (float*)d_out;

  char* ws = (char*)d_ws;
  size_t o = 0;
  auto alloc = [&](size_t bytes) {
    size_t r = o;
    o += (bytes + 255) & ~(size_t)255;
    return r;
  };
  f16* xb     = (f16*)(ws + alloc((size_t)T_TOK * D_IN * 2));               // 16MB
  f16* wgut   = (f16*)(ws + alloc((size_t)E_EXP * 2 * H_HID * D_IN * 2));   // 128MB
  f16* wdt    = (f16*)(ws + alloc((size_t)E_EXP * D_IN * H_HID * 2));       // 64MB
  f16* hbuf   = (f16*)(ws + alloc((size_t)NSLOT_PAD * H_HID * 2));          // 135MB
  int* eidx   = (int*)(ws + alloc((size_t)T_TOK * 4));
  float2* pval= (float2*)(ws + alloc((size_t)T_TOK * 8));
  int* counts = (int*)(ws + alloc(64 * 4));
  int* cursors = counts + 8;
  int* offsets = counts + 16;
  int* perm   = (int*)(ws + alloc((size_t)NSLOT_PAD * 4));
  float* gatew= (float*)(ws + alloc((size_t)NSLOT_PAD * 4));
  int2* slotAB= (int2*)(ws + alloc((size_t)T_TOK * 8));
  // ypart aliases xb+wgut (both dead after ffn1): 4*34MB = 136MB <= 144MB.
  f16* ypart  = xb;

  hipMemsetAsync(counts, 0, 64 * 4, stream);

  router_kernel<<<T_TOK / 4, 256, 0, stream>>>(x, Wr, br, eidx, pval, counts, xb);
  scan_kernel<<<1, 64, 0, stream>>>(counts, offsets);
  scatter_kernel<<<T_TOK / 256, 256, 0, stream>>>(eidx, pval, offsets, cursors,
                                                  perm, gatew, slotAB);
  transpose_cvt_kernel<1><<<dim3(H_HID / 32, D_IN / 32, E_EXP), 256, 0, stream>>>(
      Wg, wgut, D_IN, H_HID, (size_t)2 * H_HID * D_IN);
  transpose_cvt_kernel<2><<<dim3(H_HID / 32, D_IN / 32, E_EXP), 256, 0, stream>>>(
      Wu, wgut, D_IN, H_HID, (size_t)2 * H_HID * D_IN);
  // FFN1: 8192 blocks, XCD-panel affinity.
  ffn_8ph_kernel<0><<<dim3(8192), 512, 0, stream>>>(
      xb, wgut, bg, bu, offsets, perm, nullptr, hbuf);
  // Wd transpose after ffn1 keeps wdt out of the cache during ffn1.
  transpose_cvt_kernel<0><<<dim3(D_IN / 32, H_HID / 32, E_EXP), 256, 0, stream>>>(
      Wd, wdt, H_HID, D_IN, (size_t)D_IN * H_HID);
  // FFN2: 4096 blocks, split-K=4, disjoint f16 partials (no atomics).
  ffn_8ph_kernel<1><<<dim3(4096), 512, 0, stream>>>(
      hbuf, wdt, bd, nullptr, offsets, nullptr, gatew, ypart);
  combine_kernel<<<T_TOK * D_IN / 8 / 256, 256, 0, stream>>>(ypart, slotAB, out);
}

// Round 12
// 955.334 us; speedup vs baseline: 1.1472x; 1.1472x over previous
//
#include <hip/hip_runtime.h>
#include <hip/hip_fp16.h>

// MoE: B=4 S=2048 D=1024 E=8 K=2 H=4096. T=8192 tokens, 16384 assignments.
// R12: (a) FFN inner loop reverted to R8-exact (R11's fence/order changes
// regressed). (b) LDS-repack epilogues: acc -> LDS f16 tile -> coalesced
// f16x8 row stores (was 2B scatter, half of every 64B line wasted -- R9
// WRITE 275MB @1.2TB/s showed epilogue write-bound). (c) transpose kernels
// rewritten 128x32 with f16x8 coalesced writes (~1.4 -> ~4 TB/s).

#define T_TOK 8192
#define D_IN  1024
#define E_EXP 8
#define H_HID 4096
#define NSLOT (T_TOK * 2)
#define NSLOT_PAD (NSLOT + 256)
#define KSPLIT 4

typedef _Float16 f16;
typedef __attribute__((ext_vector_type(8))) _Float16 f16x8;
typedef __attribute__((ext_vector_type(4))) _Float16 f16x4;
typedef __attribute__((ext_vector_type(4))) float f32x4;

__device__ __forceinline__ void gload_lds16(const void* g, void* l) {
  __builtin_amdgcn_global_load_lds(
      (const __attribute__((address_space(1))) unsigned int*)g,
      (__attribute__((address_space(3))) unsigned int*)l, 16, 0, 0);
}

// ---------------- weight transpose (coalesced f16x8 writes) ----------------
// src [e][R][C] f32 -> dst f16 [e][ro][R]; MAP0: ro=c; MAP1 gate / MAP2 up
// interleave (16-col groups). Tile 128 src-rows x 32 src-cols.
template<int MAP>
__global__ __launch_bounds__(256) void transpose_cvt_kernel(
    const float* __restrict__ src, f16* __restrict__ dst, int R, int C,
    size_t dstride) {
  __shared__ float tile[128][33];
  int b = blockIdx.z;
  const float* s = src + (size_t)b * R * C;
  f16* d = dst + (size_t)b * dstride;
  int c0 = blockIdx.x * 32, r0 = blockIdx.y * 128;
#pragma unroll
  for (int i = 0; i < 4; ++i) {
    int q = i * 256 + threadIdx.x;     // float4 index, 1024 = 128 rows x 8
    int r = q >> 3, c4 = (q & 7) * 4;
    float4 v = *(const float4*)(s + (size_t)(r0 + r) * C + c0 + c4);
    tile[r][c4 + 0] = v.x; tile[r][c4 + 1] = v.y;
    tile[r][c4 + 2] = v.z; tile[r][c4 + 3] = v.w;
  }
  __syncthreads();
#pragma unroll
  for (int i = 0; i < 2; ++i) {
    int w = i * 256 + threadIdx.x;     // 512 items = 32 cols x 16 octets
    int col = w >> 4, oct = w & 15;
    int c = c0 + col;
    int ro = (MAP == 0) ? c : (((c >> 4) << 5) + ((MAP == 2) ? 16 : 0) + (c & 15));
    f16x8 o;
#pragma unroll
    for (int k = 0; k < 8; ++k) o[k] = (f16)tile[oct * 8 + k][col];
    *(f16x8*)(d + (size_t)ro * R + r0 + oct * 8) = o;
  }
}

// ---------------- router (+ x -> f16 conversion fused) ----------------

__global__ __launch_bounds__(256) void router_kernel(
    const float* __restrict__ x, const float* __restrict__ Wr,
    const float* __restrict__ br, int* __restrict__ eidx,
    float2* __restrict__ pval, int* __restrict__ counts,
    f16* __restrict__ xb) {
  int lane = threadIdx.x & 63, wid = threadIdx.x >> 6;
  int t = blockIdx.x * 4 + wid;
  const float* xr = x + (size_t)t * D_IN;
  float s[8] = {0.f, 0.f, 0.f, 0.f, 0.f, 0.f, 0.f, 0.f};
  int dbase = lane * 16;
#pragma unroll
  for (int i = 0; i < 4; ++i) {
    float4 xv = *(const float4*)(xr + dbase + i * 4);
    f16x4 xo = {(f16)xv.x, (f16)xv.y, (f16)xv.z, (f16)xv.w};
    *(f16x4*)(xb + (size_t)t * D_IN + dbase + i * 4) = xo;
    const float xs[4] = {xv.x, xv.y, xv.z, xv.w};
#pragma unroll
    for (int j = 0; j < 4; ++j) {
      const float* wr = Wr + (size_t)(dbase + i * 4 + j) * E_EXP;
      float4 w0 = *(const float4*)wr;
      float4 w1 = *(const float4*)(wr + 4);
      float xvj = xs[j];
      s[0] += xvj * w0.x; s[1] += xvj * w0.y; s[2] += xvj * w0.z; s[3] += xvj * w0.w;
      s[4] += xvj * w1.x; s[5] += xvj * w1.y; s[6] += xvj * w1.z; s[7] += xvj * w1.w;
    }
  }
#pragma unroll
  for (int off = 32; off; off >>= 1)
#pragma unroll
    for (int e = 0; e < 8; ++e) s[e] += __shfl_xor(s[e], off);
  if (lane == 0) {
    float v[8];
#pragma unroll
    for (int e = 0; e < 8; ++e) v[e] = s[e] + br[e];
    int i0 = 0; float v0 = v[0];
#pragma unroll
    for (int e = 1; e < 8; ++e) if (v[e] > v0) { v0 = v[e]; i0 = e; }
    int i1 = -1; float v1 = -1e30f;
#pragma unroll
    for (int e = 0; e < 8; ++e)
      if (e != i0 && v[e] > v1) { v1 = v[e]; i1 = e; }
    float ed = __expf(v1 - v0);
    float inv = 1.f / (1.f + ed);
    eidx[t] = i0 | (i1 << 8);
    pval[t] = make_float2(inv, ed * inv);
    atomicAdd(&counts[i0], 1);
    atomicAdd(&counts[i1], 1);
  }
}

__global__ void scan_kernel(const int* __restrict__ counts, int* __restrict__ offsets) {
  if (threadIdx.x == 0) {
    int acc = 0;
#pragma unroll
    for (int e = 0; e < E_EXP; ++e) { offsets[e] = acc; acc += counts[e]; }
    offsets[E_EXP] = acc;
  }
}

__global__ __launch_bounds__(256) void scatter_kernel(
    const int* __restrict__ eidx, const float2* __restrict__ pval,
    const int* __restrict__ offsets, int* __restrict__ cursors,
    int* __restrict__ perm, float* __restrict__ gatew, int2* __restrict__ slotAB) {
  int t = blockIdx.x * 256 + threadIdx.x;
  if (t >= T_TOK) return;
  int ei = eidx[t];
  float2 p = pval[t];
  int e0 = ei & 0xff, e1 = (ei >> 8) & 0xff;
  int s0 = offsets[e0] + atomicAdd(&cursors[e0], 1);
  perm[s0] = t; gatew[s0] = p.x;
  int s1 = offsets[e1] + atomicAdd(&cursors[e1], 1);
  perm[s1] = t; gatew[s1] = p.y;
  slotAB[t] = make_int2(s0, s1);
}

// ---------------- 8-phase 256x256 grouped GEMM ----------------
// R8 schedule (proven): vmcnt(6)@prologue, vmcnt(4)@P4-end, vmcnt(6)@P8-end.
// R12: epilogue repacks acc through LDS (dead after vmcnt(0)+BAR) for
// fully-coalesced f16x8 row stores.

#define SB0 __builtin_amdgcn_sched_barrier(0)
#define BAR do { SB0; __builtin_amdgcn_s_barrier(); SB0; } while (0)
#define VMCNT(N) asm volatile("s_waitcnt vmcnt(" #N ")" ::: "memory")

#define STAGE_(B, ISB, H, KT, BASE) do {                                   \
  char* d_ = smem + (B)*65536 + (ISB)*32768 + (H)*16384 + wid*1024;        \
  gload_lds16(BASE[(H)*2+0] + (size_t)(KT)*64, d_);                        \
  gload_lds16(BASE[(H)*2+1] + (size_t)(KT)*64, d_ + 8192);                 \
} while (0)

#define LDA_(B, Q)                                                          \
  _Pragma("unroll")                                                         \
  for (int m_ = 0; m_ < 4; ++m_) {                                          \
    fa[m_][0] = *(const f16x8*)(smem + (B)*65536 + aoff + ((Q)*4+m_)*2048 + offk0); \
    fa[m_][1] = *(const f16x8*)(smem + (B)*65536 + aoff + ((Q)*4+m_)*2048 + offk1); \
  }

#define LDB_(FB, B, RH)                                                     \
  _Pragma("unroll")                                                         \
  for (int n_ = 0; n_ < 2; ++n_) {                                          \
    FB[n_][0] = *(const f16x8*)(smem + (B)*65536 + 32768 + boff + ((RH)*2+n_)*2048 + offk0); \
    FB[n_][1] = *(const f16x8*)(smem + (B)*65536 + 32768 + boff + ((RH)*2+n_)*2048 + offk1); \
  }

#define QUAD_(Q, RH, FB)                                                    \
  __builtin_amdgcn_s_setprio(1);                                            \
  _Pragma("unroll")                                                         \
  for (int m_ = 0; m_ < 4; ++m_)                                            \
    _Pragma("unroll")                                                       \
    for (int n_ = 0; n_ < 2; ++n_) {                                        \
      acc[(Q)*4+m_][(RH)*2+n_] = __builtin_amdgcn_mfma_f32_16x16x32_f16(    \
          fa[m_][0], FB[n_][0], acc[(Q)*4+m_][(RH)*2+n_], 0, 0, 0);         \
      acc[(Q)*4+m_][(RH)*2+n_] = __builtin_amdgcn_mfma_f32_16x16x32_f16(    \
          fa[m_][1], FB[n_][1], acc[(Q)*4+m_][(RH)*2+n_], 0, 0, 0);         \
    }                                                                       \
  __builtin_amdgcn_s_setprio(0);

template<int MODE>
__global__ __launch_bounds__(512, 2) void ffn_8ph_kernel(
    const f16* __restrict__ Asrc, const f16* __restrict__ Bsrc,
    const float* __restrict__ bias0, const float* __restrict__ bias1,
    const int* __restrict__ offsets, const int* __restrict__ perm,
    const float* __restrict__ gatew, f16* __restrict__ dst) {
  constexpr int KD = MODE ? H_HID : D_IN;
  constexpr int BROWS = MODE ? D_IN : 2 * H_HID;
  constexpr int NT = 16;

  __shared__ __align__(16) char smem[131072];

  int g = blockIdx.x;
  int xcd = g & 7;
  int mt = (g >> 3) & 31;
  int e, nt, kc;
  if constexpr (MODE == 0) {
    int panel = xcd + 8 * (g >> 8);   // [0,256)
    e = panel >> 5; nt = panel & 31; kc = 0;
  } else {
    int sp = xcd + 8 * (g >> 8);      // [0,128)
    e = sp >> 4; nt = (sp >> 2) & 3; kc = sp & 3;
  }

  int off = offsets[e];
  int cnt = offsets[e + 1] - off;
  if (mt * 256 >= cnt) return;

  int tid = threadIdx.x, lane = tid & 63, wid = tid >> 6;
  int wm = wid >> 2, wn = wid & 3;
  int l15 = lane & 15, lc0 = lane >> 4, s7 = l15 & 7;
  int aoff = (wm * 128 + l15) * 128;
  int boff = (wn * 64 + l15) * 128;
  int offk0 = ((lc0) ^ s7) * 16;
  int offk1 = ((lc0 + 4) ^ s7) * 16;

  int rowh_[2], lc_[2];
#pragma unroll
  for (int i = 0; i < 2; ++i) {
    int chunk = (i * 8 + wid) * 64 + lane;
    rowh_[i] = chunk >> 3;
    lc_[i] = (chunk & 7) ^ (rowh_[i] & 7);
  }

  const f16 *aB[4], *bB[4];
#pragma unroll
  for (int h = 0; h < 2; ++h)
#pragma unroll
    for (int i = 0; i < 2; ++i) {
      int absrow = h * 128 + rowh_[i];
      bB[h * 2 + i] = Bsrc + ((size_t)e * BROWS + nt * 256 + absrow) * KD +
                      kc * 1024 + lc_[i] * 8;
      int slot = off + min(mt * 256 + absrow, cnt - 1);
      if constexpr (MODE == 0)
        aB[h * 2 + i] = Asrc + (size_t)perm[slot] * KD + lc_[i] * 8;
      else
        aB[h * 2 + i] = Asrc + (size_t)slot * KD + kc * 1024 + lc_[i] * 8;
    }

  float bv0[4], bv1[2];
  if constexpr (MODE == 0) {
#pragma unroll
    for (int p = 0; p < 2; ++p) {
      int h = nt * 128 + wn * 32 + p * 16 + l15;
      bv0[p] = bias0[e * H_HID + h];
      bv1[p] = bias1[e * H_HID + h];
    }
  } else {
#pragma unroll
    for (int n = 0; n < 4; ++n)
      bv0[n] = (kc == 0)
                   ? bias0[e * D_IN + nt * 256 + wn * 64 + n * 16 + l15]
                   : 0.f;
  }

  f32x4 acc[8][4] = {};
  f16x8 fa[4][2], fb01[2][2], fb23[2][2];

  // prologue: buf0.B, buf0.A (t0); buf1.B (t1); buf1.A-H0 (t1) — 14 loads.
  STAGE_(0, 1, 0, 0, bB); STAGE_(0, 1, 1, 0, bB);
  STAGE_(0, 0, 0, 0, aB); STAGE_(0, 0, 1, 0, aB);
  STAGE_(1, 1, 0, 1, bB); STAGE_(1, 1, 1, 1, bB);
  STAGE_(1, 0, 0, 1, aB);
  VMCNT(6);
  BAR;

  for (int it = 0; it < NT / 2; ++it) {
    int b_ = 2 * it + 1;
    int a2 = min(2 * it + 2, NT - 1);
    int b2 = min(2 * it + 3, NT - 1);
    // P1
    LDA_(0, 0); LDB_(fb01, 0, 0); STAGE_(1, 0, 1, b_, aB);
    BAR; QUAD_(0, 0, fb01); BAR;
    // P2
    LDB_(fb23, 0, 1);
    BAR; QUAD_(0, 1, fb23); BAR;
    // P3
    LDA_(0, 1); STAGE_(0, 1, 0, a2, bB);
    BAR; QUAD_(1, 0, fb01); BAR;
    // P4
    STAGE_(0, 1, 1, a2, bB);
    BAR; QUAD_(1, 1, fb23);
    VMCNT(4);
    BAR;
    // P5
    LDA_(1, 0); LDB_(fb01, 1, 0); STAGE_(0, 0, 0, a2, aB);
    BAR; QUAD_(0, 0, fb01); BAR;
    // P6
    LDB_(fb23, 1, 1); STAGE_(0, 0, 1, a2, aB);
    BAR; QUAD_(0, 1, fb23); BAR;
    // P7
    LDA_(1, 1); STAGE_(1, 1, 0, b2, bB);
    BAR; QUAD_(1, 0, fb01); BAR;
    // P8
    STAGE_(1, 1, 1, b2, bB); STAGE_(1, 0, 0, b2, aB);
    BAR; QUAD_(1, 1, fb23);
    VMCNT(6);
    BAR;
  }

  // drain ALL staging loads before reusing LDS for the repack tile
  VMCNT(0);
  BAR;

  int c0_ = lc0 * 4;
  f16* tile = (f16*)smem;
  if constexpr (MODE == 0) {
    // repack: [256][128] f16 (64KB)
#pragma unroll
    for (int p = 0; p < 2; ++p) {
      int colL = wn * 32 + p * 16 + l15;
#pragma unroll
      for (int m = 0; m < 8; ++m) {
        int row = wm * 128 + m * 16 + c0_;
#pragma unroll
        for (int r = 0; r < 4; ++r) {
          float gv = acc[m][2 * p][r] + bv0[p];
          float uv = acc[m][2 * p + 1][r] + bv1[p];
          tile[(row + r) * 128 + colL] = (f16)((gv / (1.f + __expf(-gv))) * uv);
        }
      }
    }
    BAR;
    // coalesced store: 4096 chunks of 16B = 256 rows x 16
    f16* dbase = dst + (size_t)(off + mt * 256) * H_HID + nt * 128;
#pragma unroll
    for (int i = 0; i < 8; ++i) {
      int linear = i * 512 + tid;
      int row = linear >> 4, c16 = linear & 15;
      if (mt * 256 + row < cnt) {
        f16x8 v = *(const f16x8*)&tile[row * 128 + c16 * 8];
        __builtin_nontemporal_store(v, (f16x8*)(dbase + (size_t)row * H_HID + c16 * 8));
      }
    }
  } else {
    // repack: [256][256] f16 (128KB)
#pragma unroll
    for (int n = 0; n < 4; ++n) {
      int colL = wn * 64 + n * 16 + l15;
#pragma unroll
      for (int m = 0; m < 8; ++m) {
        int row = wm * 128 + m * 16 + c0_;
#pragma unroll
        for (int r = 0; r < 4; ++r) {
          int slot = off + min(mt * 256 + row + r, cnt - 1);
          tile[(row + r) * 256 + colL] =
              (f16)(gatew[slot] * (acc[m][n][r] + bv0[n]));
        }
      }
    }
    BAR;
    // coalesced store: 8192 chunks = 256 rows x 32
    f16* dstP = dst + (size_t)kc * NSLOT_PAD * D_IN;
    f16* dbase = dstP + (size_t)(off + mt * 256) * D_IN + nt * 256;
#pragma unroll
    for (int i = 0; i < 16; ++i) {
      int linear = i * 512 + tid;
      int row = linear >> 5, c16 = linear & 31;
      if (mt * 256 + row < cnt) {
        f16x8 v = *(const f16x8*)&tile[row * 256 + c16 * 8];
        __builtin_nontemporal_store(v, (f16x8*)(dbase + (size_t)row * D_IN + c16 * 8));
      }
    }
  }
}

// ------- combine: out[t] = sum over s in {s0,s1}, kc in [0,4) of partial -------
__global__ __launch_bounds__(256) void combine_kernel(
    const f16* __restrict__ ypart, const int2* __restrict__ slotAB,
    float* __restrict__ out) {
  int i = blockIdx.x * 256 + threadIdx.x;
  int t = i >> 7;
  int c8 = i & 127;
  int2 s = slotAB[t];
  float sum[8] = {0.f, 0.f, 0.f, 0.f, 0.f, 0.f, 0.f, 0.f};
#pragma unroll
  for (int kc = 0; kc < KSPLIT; ++kc) {
    const f16* base = ypart + (size_t)kc * NSLOT_PAD * D_IN + c8 * 8;
    f16x8 y0 = *(const f16x8*)(base + (size_t)s.x * D_IN);
    f16x8 y1 = *(const f16x8*)(base + (size_t)s.y * D_IN);
#pragma unroll
    for (int j = 0; j < 8; ++j) sum[j] += (float)y0[j] + (float)y1[j];
  }
  float* o = out + (size_t)t * D_IN + c8 * 8;
  f32x4 o0 = {sum[0], sum[1], sum[2], sum[3]};
  f32x4 o1 = {sum[4], sum[5], sum[6], sum[7]};
  __builtin_nontemporal_store(o0, (f32x4*)o);
  __builtin_nontemporal_store(o1, (f32x4*)(o + 4));
}

// ---------------- launch ----------------

extern "C" void kernel_launch(void* const* d_in, const int* in_sizes, int n_in,
                              void* d_out, int out_size, void* d_ws, size_t ws_size,
                              hipStream_t stream) {
  const float* x  = (const float*)d_in[0];
  const float* Wr = (const float*)d_in[1];
  const float* br = (const float*)d_in[2];
  const float* Wg = (const float*)d_in[3];
  const float* bg = (const float*)d_in[4];
  const float* Wu = (const float*)d_in[5];
  const float* bu = (const float*)d_in[6];
  const float* Wd = (const float*)d_in[7];
  const float* bd = (const float*)d_in[8];
  float* out = (float*)d_out;

  char* ws = (char*)d_ws;
  size_t o = 0;
  auto alloc = [&](size_t bytes) {
    size_t r = o;
    o += (bytes + 255) & ~(size_t)255;
    return r;
  };
  f16* xb     = (f16*)(ws + alloc((size_t)T_TOK * D_IN * 2));               // 16MB
  f16* wgut   = (f16*)(ws + alloc((size_t)E_EXP * 2 * H_HID * D_IN * 2));   // 128MB
  f16* wdt    = (f16*)(ws + alloc((size_t)E_EXP * D_IN * H_HID * 2));       // 64MB
  f16* hbuf   = (f16*)(ws + alloc((size_t)NSLOT_PAD * H_HID * 2));          // 135MB
  int* eidx   = (int*)(ws + alloc((size_t)T_TOK * 4));
  float2* pval= (float2*)(ws + alloc((size_t)T_TOK * 8));
  int* counts = (int*)(ws + alloc(64 * 4));
  int* cursors = counts + 8;
  int* offsets = counts + 16;
  int* perm   = (int*)(ws + alloc((size_t)NSLOT_PAD * 4));
  float* gatew= (float*)(ws + alloc((size_t)NSLOT_PAD * 4));
  int2* slotAB= (int2*)(ws + alloc((size_t)T_TOK * 8));
  // ypart aliases xb+wgut (both dead after ffn1): 4*34MB = 136MB <= 144MB.
  f16* ypart  = xb;

  hipMemsetAsync(counts, 0, 64 * 4, stream);

  router_kernel<<<T_TOK / 4, 256, 0, stream>>>(x, Wr, br, eidx, pval, counts, xb);
  scan_kernel<<<1, 64, 0, stream>>>(counts, offsets);
  scatter_kernel<<<T_TOK / 256, 256, 0, stream>>>(eidx, pval, offsets, cursors,
                                                  perm, gatew, slotAB);
  transpose_cvt_kernel<1><<<dim3(H_HID / 32, D_IN / 128, E_EXP), 256, 0, stream>>>(
      Wg, wgut, D_IN, H_HID, (size_t)2 * H_HID * D_IN);
  transpose_cvt_kernel<2><<<dim3(H_HID / 32, D_IN / 128, E_EXP), 256, 0, stream>>>(
      Wu, wgut, D_IN, H_HID, (size_t)2 * H_HID * D_IN);
  // FFN1: 8192 blocks, XCD-panel affinity.
  ffn_8ph_kernel<0><<<dim3(8192), 512, 0, stream>>>(
      xb, wgut, bg, bu, offsets, perm, nullptr, hbuf);
  // Wd transpose after ffn1 keeps wdt out of the cache during ffn1.
  transpose_cvt_kernel<0><<<dim3(D_IN / 32, H_HID / 128, E_EXP), 256, 0, stream>>>(
      Wd, wdt, H_HID, D_IN, (size_t)D_IN * H_HID);
  // FFN2: 4096 blocks, split-K=4, disjoint f16 partials (no atomics).
  ffn_8ph_kernel<1><<<dim3(4096), 512, 0, stream>>>(
      hbuf, wdt, bd, nullptr, offsets, nullptr, gatew, ypart);
  combine_kernel<<<T_TOK * D_IN / 8 / 256, 256, 0, stream>>>(ypart, slotAB, out);
}

// Round 13
// 928.665 us; speedup vs baseline: 1.1801x; 1.0287x over previous
//
#include <hip/hip_runtime.h>
#include <hip/hip_fp16.h>

// MoE: B=4 S=2048 D=1024 E=8 K=2 H=4096. T=8192 tokens, 16384 assignments.
// R13: (1) ISOLATED main-loop change: BAR sched_barrier(0) -> memory-fence
// only (m201 template has no SB0 in the loop; R3 added it untested; R11's
// test was confounded with a QUAD reorder). QUAD/schedule/epilogue = R12.
// (2) prep super-kernel fuses router + Wg/Wu/Wd transposes (serial glue).

#define T_TOK 8192
#define D_IN  1024
#define E_EXP 8
#define H_HID 4096
#define NSLOT (T_TOK * 2)
#define NSLOT_PAD (NSLOT + 256)
#define KSPLIT 4

typedef _Float16 f16;
typedef __attribute__((ext_vector_type(8))) _Float16 f16x8;
typedef __attribute__((ext_vector_type(4))) _Float16 f16x4;
typedef __attribute__((ext_vector_type(4))) float f32x4;

__device__ __forceinline__ void gload_lds16(const void* g, void* l) {
  __builtin_amdgcn_global_load_lds(
      (const __attribute__((address_space(1))) unsigned int*)g,
      (__attribute__((address_space(3))) unsigned int*)l, 16, 0, 0);
}

// ---------------- prep: router (+x->f16) AND weight transposes, fused ----------------
// blocks [0,2048): router; [2048,2048+8192): Wg (MAP1); next 8192: Wu (MAP2);
// next 8192: Wd (MAP0). Transpose tile: 128 src-rows x 32 src-cols,
// coalesced f16x8 writes.

__global__ __launch_bounds__(256) void prep_kernel(
    const float* __restrict__ x, const float* __restrict__ Wr,
    const float* __restrict__ br, const float* __restrict__ Wg,
    const float* __restrict__ Wu, const float* __restrict__ Wd,
    int* __restrict__ eidx, float2* __restrict__ pval,
    int* __restrict__ counts, f16* __restrict__ xb,
    f16* __restrict__ wgut, f16* __restrict__ wdt) {
  __shared__ float tile[128][33];
  int g = blockIdx.x;
  if (g < T_TOK / 4) {
    // ---- router part ----
    int lane = threadIdx.x & 63, wid = threadIdx.x >> 6;
    int t = g * 4 + wid;
    const float* xr = x + (size_t)t * D_IN;
    float s[8] = {0.f, 0.f, 0.f, 0.f, 0.f, 0.f, 0.f, 0.f};
    int dbase = lane * 16;
#pragma unroll
    for (int i = 0; i < 4; ++i) {
      float4 xv = *(const float4*)(xr + dbase + i * 4);
      f16x4 xo = {(f16)xv.x, (f16)xv.y, (f16)xv.z, (f16)xv.w};
      *(f16x4*)(xb + (size_t)t * D_IN + dbase + i * 4) = xo;
      const float xs[4] = {xv.x, xv.y, xv.z, xv.w};
#pragma unroll
      for (int j = 0; j < 4; ++j) {
        const float* wr = Wr + (size_t)(dbase + i * 4 + j) * E_EXP;
        float4 w0 = *(const float4*)wr;
        float4 w1 = *(const float4*)(wr + 4);
        float xvj = xs[j];
        s[0] += xvj * w0.x; s[1] += xvj * w0.y; s[2] += xvj * w0.z; s[3] += xvj * w0.w;
        s[4] += xvj * w1.x; s[5] += xvj * w1.y; s[6] += xvj * w1.z; s[7] += xvj * w1.w;
      }
    }
#pragma unroll
    for (int off = 32; off; off >>= 1)
#pragma unroll
      for (int e = 0; e < 8; ++e) s[e] += __shfl_xor(s[e], off);
    if (lane == 0) {
      float v[8];
#pragma unroll
      for (int e = 0; e < 8; ++e) v[e] = s[e] + br[e];
      int i0 = 0; float v0 = v[0];
#pragma unroll
      for (int e = 1; e < 8; ++e) if (v[e] > v0) { v0 = v[e]; i0 = e; }
      int i1 = -1; float v1 = -1e30f;
#pragma unroll
      for (int e = 0; e < 8; ++e)
        if (e != i0 && v[e] > v1) { v1 = v[e]; i1 = e; }
      float ed = __expf(v1 - v0);
      float inv = 1.f / (1.f + ed);
      eidx[t] = i0 | (i1 << 8);
      pval[t] = make_float2(inv, ed * inv);
      atomicAdd(&counts[i0], 1);
      atomicAdd(&counts[i1], 1);
    }
    return;
  }
  // ---- transpose part ----
  int i = g - T_TOK / 4;
  int which = i >> 13;          // 0=Wg, 1=Wu, 2=Wd
  int j = i & 8191;
  const float* src; f16* dst; int R, C, MAP, cx, cy, e; size_t dstride;
  if (which < 2) {
    cx = j & 127; cy = (j >> 7) & 7; e = j >> 10;
    R = D_IN; C = H_HID; dstride = (size_t)2 * H_HID * D_IN;
    dst = wgut; src = (which == 0) ? Wg : Wu; MAP = which + 1;
  } else {
    cx = j & 31; cy = (j >> 5) & 31; e = j >> 10;
    R = H_HID; C = D_IN; dstride = (size_t)D_IN * H_HID;
    dst = wdt; src = Wd; MAP = 0;
  }
  const float* s = src + (size_t)e * R * C;
  f16* d = dst + (size_t)e * dstride;
  int c0 = cx * 32, r0 = cy * 128;
#pragma unroll
  for (int q4 = 0; q4 < 4; ++q4) {
    int q = q4 * 256 + threadIdx.x;
    int r = q >> 3, c4 = (q & 7) * 4;
    float4 v = *(const float4*)(s + (size_t)(r0 + r) * C + c0 + c4);
    tile[r][c4 + 0] = v.x; tile[r][c4 + 1] = v.y;
    tile[r][c4 + 2] = v.z; tile[r][c4 + 3] = v.w;
  }
  __syncthreads();
#pragma unroll
  for (int w2 = 0; w2 < 2; ++w2) {
    int w = w2 * 256 + threadIdx.x;
    int col = w >> 4, oct = w & 15;
    int c = c0 + col;
    int ro = (MAP == 0) ? c : (((c >> 4) << 5) + ((MAP == 2) ? 16 : 0) + (c & 15));
    f16x8 o;
#pragma unroll
    for (int k = 0; k < 8; ++k) o[k] = (f16)tile[oct * 8 + k][col];
    *(f16x8*)(d + (size_t)ro * R + r0 + oct * 8) = o;
  }
}

__global__ void scan_kernel(const int* __restrict__ counts, int* __restrict__ offsets) {
  if (threadIdx.x == 0) {
    int acc = 0;
#pragma unroll
    for (int e = 0; e < E_EXP; ++e) { offsets[e] = acc; acc += counts[e]; }
    offsets[E_EXP] = acc;
  }
}

__global__ __launch_bounds__(256) void scatter_kernel(
    const int* __restrict__ eidx, const float2* __restrict__ pval,
    const int* __restrict__ offsets, int* __restrict__ cursors,
    int* __restrict__ perm, float* __restrict__ gatew, int2* __restrict__ slotAB) {
  int t = blockIdx.x * 256 + threadIdx.x;
  if (t >= T_TOK) return;
  int ei = eidx[t];
  float2 p = pval[t];
  int e0 = ei & 0xff, e1 = (ei >> 8) & 0xff;
  int s0 = offsets[e0] + atomicAdd(&cursors[e0], 1);
  perm[s0] = t; gatew[s0] = p.x;
  int s1 = offsets[e1] + atomicAdd(&cursors[e1], 1);
  perm[s1] = t; gatew[s1] = p.y;
  slotAB[t] = make_int2(s0, s1);
}

// ---------------- 8-phase 256x256 grouped GEMM ----------------
// R8 schedule; R12 repack epilogue; R13 BAR = memory fence only (no SB0).

#define BAR do {                              \
  asm volatile("" ::: "memory");              \
  __builtin_amdgcn_s_barrier();               \
  asm volatile("" ::: "memory");              \
} while (0)
#define VMCNT(N) asm volatile("s_waitcnt vmcnt(" #N ")" ::: "memory")

#define STAGE_(B, ISB, H, KT, BASE) do {                                   \
  char* d_ = smem + (B)*65536 + (ISB)*32768 + (H)*16384 + wid*1024;        \
  gload_lds16(BASE[(H)*2+0] + (size_t)(KT)*64, d_);                        \
  gload_lds16(BASE[(H)*2+1] + (size_t)(KT)*64, d_ + 8192);                 \
} while (0)

#define LDA_(B, Q)                                                          \
  _Pragma("unroll")                                                         \
  for (int m_ = 0; m_ < 4; ++m_) {                                          \
    fa[m_][0] = *(const f16x8*)(smem + (B)*65536 + aoff + ((Q)*4+m_)*2048 + offk0); \
    fa[m_][1] = *(const f16x8*)(smem + (B)*65536 + aoff + ((Q)*4+m_)*2048 + offk1); \
  }

#define LDB_(FB, B, RH)                                                     \
  _Pragma("unroll")                                                         \
  for (int n_ = 0; n_ < 2; ++n_) {                                          \
    FB[n_][0] = *(const f16x8*)(smem + (B)*65536 + 32768 + boff + ((RH)*2+n_)*2048 + offk0); \
    FB[n_][1] = *(const f16x8*)(smem + (B)*65536 + 32768 + boff + ((RH)*2+n_)*2048 + offk1); \
  }

#define QUAD_(Q, RH, FB)                                                    \
  __builtin_amdgcn_s_setprio(1);                                            \
  _Pragma("unroll")                                                         \
  for (int m_ = 0; m_ < 4; ++m_)                                            \
    _Pragma("unroll")                                                       \
    for (int n_ = 0; n_ < 2; ++n_) {                                        \
      acc[(Q)*4+m_][(RH)*2+n_] = __builtin_amdgcn_mfma_f32_16x16x32_f16(    \
          fa[m_][0], FB[n_][0], acc[(Q)*4+m_][(RH)*2+n_], 0, 0, 0);         \
      acc[(Q)*4+m_][(RH)*2+n_] = __builtin_amdgcn_mfma_f32_16x16x32_f16(    \
          fa[m_][1], FB[n_][1], acc[(Q)*4+m_][(RH)*2+n_], 0, 0, 0);         \
    }                                                                       \
  __builtin_amdgcn_s_setprio(0);

template<int MODE>
__global__ __launch_bounds__(512, 2) void ffn_8ph_kernel(
    const f16* __restrict__ Asrc, const f16* __restrict__ Bsrc,
    const float* __restrict__ bias0, const float* __restrict__ bias1,
    const int* __restrict__ offsets, const int* __restrict__ perm,
    const float* __restrict__ gatew, f16* __restrict__ dst) {
  constexpr int KD = MODE ? H_HID : D_IN;
  constexpr int BROWS = MODE ? D_IN : 2 * H_HID;
  constexpr int NT = 16;

  __shared__ __align__(16) char smem[131072];

  int g = blockIdx.x;
  int xcd = g & 7;
  int mt = (g >> 3) & 31;
  int e, nt, kc;
  if constexpr (MODE == 0) {
    int panel = xcd + 8 * (g >> 8);   // [0,256)
    e = panel >> 5; nt = panel & 31; kc = 0;
  } else {
    int sp = xcd + 8 * (g >> 8);      // [0,128)
    e = sp >> 4; nt = (sp >> 2) & 3; kc = sp & 3;
  }

  int off = offsets[e];
  int cnt = offsets[e + 1] - off;
  if (mt * 256 >= cnt) return;

  int tid = threadIdx.x, lane = tid & 63, wid = tid >> 6;
  int wm = wid >> 2, wn = wid & 3;
  int l15 = lane & 15, lc0 = lane >> 4, s7 = l15 & 7;
  int aoff = (wm * 128 + l15) * 128;
  int boff = (wn * 64 + l15) * 128;
  int offk0 = ((lc0) ^ s7) * 16;
  int offk1 = ((lc0 + 4) ^ s7) * 16;

  int rowh_[2], lc_[2];
#pragma unroll
  for (int i = 0; i < 2; ++i) {
    int chunk = (i * 8 + wid) * 64 + lane;
    rowh_[i] = chunk >> 3;
    lc_[i] = (chunk & 7) ^ (rowh_[i] & 7);
  }

  const f16 *aB[4], *bB[4];
#pragma unroll
  for (int h = 0; h < 2; ++h)
#pragma unroll
    for (int i = 0; i < 2; ++i) {
      int absrow = h * 128 + rowh_[i];
      bB[h * 2 + i] = Bsrc + ((size_t)e * BROWS + nt * 256 + absrow) * KD +
                      kc * 1024 + lc_[i] * 8;
      int slot = off + min(mt * 256 + absrow, cnt - 1);
      if constexpr (MODE == 0)
        aB[h * 2 + i] = Asrc + (size_t)perm[slot] * KD + lc_[i] * 8;
      else
        aB[h * 2 + i] = Asrc + (size_t)slot * KD + kc * 1024 + lc_[i] * 8;
    }

  float bv0[4], bv1[2];
  if constexpr (MODE == 0) {
#pragma unroll
    for (int p = 0; p < 2; ++p) {
      int h = nt * 128 + wn * 32 + p * 16 + l15;
      bv0[p] = bias0[e * H_HID + h];
      bv1[p] = bias1[e * H_HID + h];
    }
  } else {
#pragma unroll
    for (int n = 0; n < 4; ++n)
      bv0[n] = (kc == 0)
                   ? bias0[e * D_IN + nt * 256 + wn * 64 + n * 16 + l15]
                   : 0.f;
  }

  f32x4 acc[8][4] = {};
  f16x8 fa[4][2], fb01[2][2], fb23[2][2];

  // prologue: buf0.B, buf0.A (t0); buf1.B (t1); buf1.A-H0 (t1) — 14 loads.
  STAGE_(0, 1, 0, 0, bB); STAGE_(0, 1, 1, 0, bB);
  STAGE_(0, 0, 0, 0, aB); STAGE_(0, 0, 1, 0, aB);
  STAGE_(1, 1, 0, 1, bB); STAGE_(1, 1, 1, 1, bB);
  STAGE_(1, 0, 0, 1, aB);
  VMCNT(6);
  BAR;

  for (int it = 0; it < NT / 2; ++it) {
    int b_ = 2 * it + 1;
    int a2 = min(2 * it + 2, NT - 1);
    int b2 = min(2 * it + 3, NT - 1);
    // P1
    LDA_(0, 0); LDB_(fb01, 0, 0); STAGE_(1, 0, 1, b_, aB);
    BAR; QUAD_(0, 0, fb01); BAR;
    // P2
    LDB_(fb23, 0, 1);
    BAR; QUAD_(0, 1, fb23); BAR;
    // P3
    LDA_(0, 1); STAGE_(0, 1, 0, a2, bB);
    BAR; QUAD_(1, 0, fb01); BAR;
    // P4
    STAGE_(0, 1, 1, a2, bB);
    BAR; QUAD_(1, 1, fb23);
    VMCNT(4);
    BAR;
    // P5
    LDA_(1, 0); LDB_(fb01, 1, 0); STAGE_(0, 0, 0, a2, aB);
    BAR; QUAD_(0, 0, fb01); BAR;
    // P6
    LDB_(fb23, 1, 1); STAGE_(0, 0, 1, a2, aB);
    BAR; QUAD_(0, 1, fb23); BAR;
    // P7
    LDA_(1, 1); STAGE_(1, 1, 0, b2, bB);
    BAR; QUAD_(1, 0, fb01); BAR;
    // P8
    STAGE_(1, 1, 1, b2, bB); STAGE_(1, 0, 0, b2, aB);
    BAR; QUAD_(1, 1, fb23);
    VMCNT(6);
    BAR;
  }

  // drain ALL staging loads before reusing LDS for the repack tile
  VMCNT(0);
  BAR;

  int c0_ = lc0 * 4;
  f16* tile = (f16*)smem;
  if constexpr (MODE == 0) {
    // repack: [256][128] f16 (64KB)
#pragma unroll
    for (int p = 0; p < 2; ++p) {
      int colL = wn * 32 + p * 16 + l15;
#pragma unroll
      for (int m = 0; m < 8; ++m) {
        int row = wm * 128 + m * 16 + c0_;
#pragma unroll
        for (int r = 0; r < 4; ++r) {
          float gv = acc[m][2 * p][r] + bv0[p];
          float uv = acc[m][2 * p + 1][r] + bv1[p];
          tile[(row + r) * 128 + colL] = (f16)((gv / (1.f + __expf(-gv))) * uv);
        }
      }
    }
    BAR;
    f16* dbase = dst + (size_t)(off + mt * 256) * H_HID + nt * 128;
#pragma unroll
    for (int i = 0; i < 8; ++i) {
      int linear = i * 512 + tid;
      int row = linear >> 4, c16 = linear & 15;
      if (mt * 256 + row < cnt) {
        f16x8 v = *(const f16x8*)&tile[row * 128 + c16 * 8];
        __builtin_nontemporal_store(v, (f16x8*)(dbase + (size_t)row * H_HID + c16 * 8));
      }
    }
  } else {
    // repack: [256][256] f16 (128KB)
#pragma unroll
    for (int n = 0; n < 4; ++n) {
      int colL = wn * 64 + n * 16 + l15;
#pragma unroll
      for (int m = 0; m < 8; ++m) {
        int row = wm * 128 + m * 16 + c0_;
#pragma unroll
        for (int r = 0; r < 4; ++r) {
          int slot = off + min(mt * 256 + row + r, cnt - 1);
          tile[(row + r) * 256 + colL] =
              (f16)(gatew[slot] * (acc[m][n][r] + bv0[n]));
        }
      }
    }
    BAR;
    f16* dstP = dst + (size_t)kc * NSLOT_PAD * D_IN;
    f16* dbase = dstP + (size_t)(off + mt * 256) * D_IN + nt * 256;
#pragma unroll
    for (int i = 0; i < 16; ++i) {
      int linear = i * 512 + tid;
      int row = linear >> 5, c16 = linear & 31;
      if (mt * 256 + row < cnt) {
        f16x8 v = *(const f16x8*)&tile[row * 256 + c16 * 8];
        __builtin_nontemporal_store(v, (f16x8*)(dbase + (size_t)row * D_IN + c16 * 8));
      }
    }
  }
}

// ------- combine: out[t] = sum over s in {s0,s1}, kc in [0,4) of partial -------
__global__ __launch_bounds__(256) void combine_kernel(
    const f16* __restrict__ ypart, const int2* __restrict__ slotAB,
    float* __restrict__ out) {
  int i = blockIdx.x * 256 + threadIdx.x;
  int t = i >> 7;
  int c8 = i & 127;
  int2 s = slotAB[t];
  float sum[8] = {0.f, 0.f, 0.f, 0.f, 0.f, 0.f, 0.f, 0.f};
#pragma unroll
  for (int kc = 0; kc < KSPLIT; ++kc) {
    const f16* base = ypart + (size_t)kc * NSLOT_PAD * D_IN + c8 * 8;
    f16x8 y0 = *(const f16x8*)(base + (size_t)s.x * D_IN);
    f16x8 y1 = *(const f16x8*)(base + (size_t)s.y * D_IN);
#pragma unroll
    for (int j = 0; j < 8; ++j) sum[j] += (float)y0[j] + (float)y1[j];
  }
  float* o = out + (size_t)t * D_IN + c8 * 8;
  f32x4 o0 = {sum[0], sum[1], sum[2], sum[3]};
  f32x4 o1 = {sum[4], sum[5], sum[6], sum[7]};
  __builtin_nontemporal_store(o0, (f32x4*)o);
  __builtin_nontemporal_store(o1, (f32x4*)(o + 4));
}

// ---------------- launch ----------------

extern "C" void kernel_launch(void* const* d_in, const int* in_sizes, int n_in,
                              void* d_out, int out_size, void* d_ws, size_t ws_size,
                              hipStream_t stream) {
  const float* x  = (const float*)d_in[0];
  const float* Wr = (const float*)d_in[1];
  const float* br = (const float*)d_in[2];
  const float* Wg = (const float*)d_in[3];
  const float* bg = (const float*)d_in[4];
  const float* Wu = (const float*)d_in[5];
  const float* bu = (const float*)d_in[6];
  const float* Wd = (const float*)d_in[7];
  const float* bd = (const float*)d_in[8];
  float* out = (float*)d_out;

  char* ws = (char*)d_ws;
  size_t o = 0;
  auto alloc = [&](size_t bytes) {
    size_t r = o;
    o += (bytes + 255) & ~(size_t)255;
    return r;
  };
  f16* xb     = (f16*)(ws + alloc((size_t)T_TOK * D_IN * 2));               // 16MB
  f16* wgut   = (f16*)(ws + alloc((size_t)E_EXP * 2 * H_HID * D_IN * 2));   // 128MB
  f16* wdt    = (f16*)(ws + alloc((size_t)E_EXP * D_IN * H_HID * 2));       // 64MB
  f16* hbuf   = (f16*)(ws + alloc((size_t)NSLOT_PAD * H_HID * 2));          // 135MB
  int* eidx   = (int*)(ws + alloc((size_t)T_TOK * 4));
  float2* pval= (float2*)(ws + alloc((size_t)T_TOK * 8));
  int* counts = (int*)(ws + alloc(64 * 4));
  int* cursors = counts + 8;
  int* offsets = counts + 16;
  int* perm   = (int*)(ws + alloc((size_t)NSLOT_PAD * 4));
  float* gatew= (float*)(ws + alloc((size_t)NSLOT_PAD * 4));
  int2* slotAB= (int2*)(ws + alloc((size_t)T_TOK * 8));
  // ypart aliases xb+wgut (both dead after ffn1): 4*34MB = 136MB <= 144MB.
  f16* ypart  = xb;

  hipMemsetAsync(counts, 0, 64 * 4, stream);

  // prep: router (2048 blocks) + Wg/Wu/Wd transposes (3 x 8192 blocks)
  prep_kernel<<<dim3(T_TOK / 4 + 3 * 8192), 256, 0, stream>>>(
      x, Wr, br, Wg, Wu, Wd, eidx, pval, counts, xb, wgut, wdt);
  scan_kernel<<<1, 64, 0, stream>>>(counts, offsets);
  scatter_kernel<<<T_TOK / 256, 256, 0, stream>>>(eidx, pval, offsets, cursors,
                                                  perm, gatew, slotAB);
  // FFN1: 8192 blocks, XCD-panel affinity.
  ffn_8ph_kernel<0><<<dim3(8192), 512, 0, stream>>>(
      xb, wgut, bg, bu, offsets, perm, nullptr, hbuf);
  // FFN2: 4096 blocks, split-K=4, disjoint f16 partials (no atomics).
  ffn_8ph_kernel<1><<<dim3(4096), 512, 0, stream>>>(
      hbuf, wdt, bd, nullptr, offsets, nullptr, gatew, ypart);
  combine_kernel<<<T_TOK * D_IN / 8 / 256, 256, 0, stream>>>(ypart, slotAB, out);
}

// Round 14
// 912.327 us; speedup vs baseline: 1.2012x; 1.0179x over previous
//
#include <hip/hip_runtime.h>
#include <hip/hip_fp16.h>

// MoE: B=4 S=2048 D=1024 E=8 K=2 H=4096. T=8192 tokens, 16384 assignments.
// R14 (isolated): main-loop barriers -> BARE __builtin_amdgcn_s_barrier()
// (m201 template form). R13's asm-memory fences around every barrier forbade
// the compiler from overlapping phase-P+1 ds_reads with phase-P MFMAs ->
// cycle audit showed MFMA+LDS+barrier SUMMING (13.6k cyc/iter vs template
// 6.6k). Hazards stay guarded: VMCNT(N) asm has memory clobber (loads can't
// cross); gload_lds/s_barrier are side-effecting intrinsics (don't reorder
// vs each other). Epilogue repack (plain cross-thread LDS ops) uses real
// __syncthreads(). All else = R13.

#define T_TOK 8192
#define D_IN  1024
#define E_EXP 8
#define H_HID 4096
#define NSLOT (T_TOK * 2)
#define NSLOT_PAD (NSLOT + 256)
#define KSPLIT 4

typedef _Float16 f16;
typedef __attribute__((ext_vector_type(8))) _Float16 f16x8;
typedef __attribute__((ext_vector_type(4))) _Float16 f16x4;
typedef __attribute__((ext_vector_type(4))) float f32x4;

__device__ __forceinline__ void gload_lds16(const void* g, void* l) {
  __builtin_amdgcn_global_load_lds(
      (const __attribute__((address_space(1))) unsigned int*)g,
      (__attribute__((address_space(3))) unsigned int*)l, 16, 0, 0);
}

// ---------------- prep: router (+x->f16) AND weight transposes, fused ----------------

__global__ __launch_bounds__(256) void prep_kernel(
    const float* __restrict__ x, const float* __restrict__ Wr,
    const float* __restrict__ br, const float* __restrict__ Wg,
    const float* __restrict__ Wu, const float* __restrict__ Wd,
    int* __restrict__ eidx, float2* __restrict__ pval,
    int* __restrict__ counts, f16* __restrict__ xb,
    f16* __restrict__ wgut, f16* __restrict__ wdt) {
  __shared__ float tile[128][33];
  int g = blockIdx.x;
  if (g < T_TOK / 4) {
    // ---- router part ----
    int lane = threadIdx.x & 63, wid = threadIdx.x >> 6;
    int t = g * 4 + wid;
    const float* xr = x + (size_t)t * D_IN;
    float s[8] = {0.f, 0.f, 0.f, 0.f, 0.f, 0.f, 0.f, 0.f};
    int dbase = lane * 16;
#pragma unroll
    for (int i = 0; i < 4; ++i) {
      float4 xv = *(const float4*)(xr + dbase + i * 4);
      f16x4 xo = {(f16)xv.x, (f16)xv.y, (f16)xv.z, (f16)xv.w};
      *(f16x4*)(xb + (size_t)t * D_IN + dbase + i * 4) = xo;
      const float xs[4] = {xv.x, xv.y, xv.z, xv.w};
#pragma unroll
      for (int j = 0; j < 4; ++j) {
        const float* wr = Wr + (size_t)(dbase + i * 4 + j) * E_EXP;
        float4 w0 = *(const float4*)wr;
        float4 w1 = *(const float4*)(wr + 4);
        float xvj = xs[j];
        s[0] += xvj * w0.x; s[1] += xvj * w0.y; s[2] += xvj * w0.z; s[3] += xvj * w0.w;
        s[4] += xvj * w1.x; s[5] += xvj * w1.y; s[6] += xvj * w1.z; s[7] += xvj * w1.w;
      }
    }
#pragma unroll
    for (int off = 32; off; off >>= 1)
#pragma unroll
      for (int e = 0; e < 8; ++e) s[e] += __shfl_xor(s[e], off);
    if (lane == 0) {
      float v[8];
#pragma unroll
      for (int e = 0; e < 8; ++e) v[e] = s[e] + br[e];
      int i0 = 0; float v0 = v[0];
#pragma unroll
      for (int e = 1; e < 8; ++e) if (v[e] > v0) { v0 = v[e]; i0 = e; }
      int i1 = -1; float v1 = -1e30f;
#pragma unroll
      for (int e = 0; e < 8; ++e)
        if (e != i0 && v[e] > v1) { v1 = v[e]; i1 = e; }
      float ed = __expf(v1 - v0);
      float inv = 1.f / (1.f + ed);
      eidx[t] = i0 | (i1 << 8);
      pval[t] = make_float2(inv, ed * inv);
      atomicAdd(&counts[i0], 1);
      atomicAdd(&counts[i1], 1);
    }
    return;
  }
  // ---- transpose part ----
  int i = g - T_TOK / 4;
  int which = i >> 13;          // 0=Wg, 1=Wu, 2=Wd
  int j = i & 8191;
  const float* src; f16* dst; int R, C, MAP, cx, cy, e; size_t dstride;
  if (which < 2) {
    cx = j & 127; cy = (j >> 7) & 7; e = j >> 10;
    R = D_IN; C = H_HID; dstride = (size_t)2 * H_HID * D_IN;
    dst = wgut; src = (which == 0) ? Wg : Wu; MAP = which + 1;
  } else {
    cx = j & 31; cy = (j >> 5) & 31; e = j >> 10;
    R = H_HID; C = D_IN; dstride = (size_t)D_IN * H_HID;
    dst = wdt; src = Wd; MAP = 0;
  }
  const float* s = src + (size_t)e * R * C;
  f16* d = dst + (size_t)e * dstride;
  int c0 = cx * 32, r0 = cy * 128;
#pragma unroll
  for (int q4 = 0; q4 < 4; ++q4) {
    int q = q4 * 256 + threadIdx.x;
    int r = q >> 3, c4 = (q & 7) * 4;
    float4 v = *(const float4*)(s + (size_t)(r0 + r) * C + c0 + c4);
    tile[r][c4 + 0] = v.x; tile[r][c4 + 1] = v.y;
    tile[r][c4 + 2] = v.z; tile[r][c4 + 3] = v.w;
  }
  __syncthreads();
#pragma unroll
  for (int w2 = 0; w2 < 2; ++w2) {
    int w = w2 * 256 + threadIdx.x;
    int col = w >> 4, oct = w & 15;
    int c = c0 + col;
    int ro = (MAP == 0) ? c : (((c >> 4) << 5) + ((MAP == 2) ? 16 : 0) + (c & 15));
    f16x8 o;
#pragma unroll
    for (int k = 0; k < 8; ++k) o[k] = (f16)tile[oct * 8 + k][col];
    *(f16x8*)(d + (size_t)ro * R + r0 + oct * 8) = o;
  }
}

__global__ void scan_kernel(const int* __restrict__ counts, int* __restrict__ offsets) {
  if (threadIdx.x == 0) {
    int acc = 0;
#pragma unroll
    for (int e = 0; e < E_EXP; ++e) { offsets[e] = acc; acc += counts[e]; }
    offsets[E_EXP] = acc;
  }
}

__global__ __launch_bounds__(256) void scatter_kernel(
    const int* __restrict__ eidx, const float2* __restrict__ pval,
    const int* __restrict__ offsets, int* __restrict__ cursors,
    int* __restrict__ perm, float* __restrict__ gatew, int2* __restrict__ slotAB) {
  int t = blockIdx.x * 256 + threadIdx.x;
  if (t >= T_TOK) return;
  int ei = eidx[t];
  float2 p = pval[t];
  int e0 = ei & 0xff, e1 = (ei >> 8) & 0xff;
  int s0 = offsets[e0] + atomicAdd(&cursors[e0], 1);
  perm[s0] = t; gatew[s0] = p.x;
  int s1 = offsets[e1] + atomicAdd(&cursors[e1], 1);
  perm[s1] = t; gatew[s1] = p.y;
  slotAB[t] = make_int2(s0, s1);
}

// ---------------- 8-phase 256x256 grouped GEMM ----------------
// R8 schedule; R12 repack epilogue; R14 BAR = bare s_barrier (template form).

#define BAR __builtin_amdgcn_s_barrier()
#define VMCNT(N) asm volatile("s_waitcnt vmcnt(" #N ")" ::: "memory")

#define STAGE_(B, ISB, H, KT, BASE) do {                                   \
  char* d_ = smem + (B)*65536 + (ISB)*32768 + (H)*16384 + wid*1024;        \
  gload_lds16(BASE[(H)*2+0] + (size_t)(KT)*64, d_);                        \
  gload_lds16(BASE[(H)*2+1] + (size_t)(KT)*64, d_ + 8192);                 \
} while (0)

#define LDA_(B, Q)                                                          \
  _Pragma("unroll")                                                         \
  for (int m_ = 0; m_ < 4; ++m_) {                                          \
    fa[m_][0] = *(const f16x8*)(smem + (B)*65536 + aoff + ((Q)*4+m_)*2048 + offk0); \
    fa[m_][1] = *(const f16x8*)(smem + (B)*65536 + aoff + ((Q)*4+m_)*2048 + offk1); \
  }

#define LDB_(FB, B, RH)                                                     \
  _Pragma("unroll")                                                         \
  for (int n_ = 0; n_ < 2; ++n_) {                                          \
    FB[n_][0] = *(const f16x8*)(smem + (B)*65536 + 32768 + boff + ((RH)*2+n_)*2048 + offk0); \
    FB[n_][1] = *(const f16x8*)(smem + (B)*65536 + 32768 + boff + ((RH)*2+n_)*2048 + offk1); \
  }

#define QUAD_(Q, RH, FB)                                                    \
  __builtin_amdgcn_s_setprio(1);                                            \
  _Pragma("unroll")                                                         \
  for (int m_ = 0; m_ < 4; ++m_)                                            \
    _Pragma("unroll")                                                       \
    for (int n_ = 0; n_ < 2; ++n_) {                                        \
      acc[(Q)*4+m_][(RH)*2+n_] = __builtin_amdgcn_mfma_f32_16x16x32_f16(    \
          fa[m_][0], FB[n_][0], acc[(Q)*4+m_][(RH)*2+n_], 0, 0, 0);         \
      acc[(Q)*4+m_][(RH)*2+n_] = __builtin_amdgcn_mfma_f32_16x16x32_f16(    \
          fa[m_][1], FB[n_][1], acc[(Q)*4+m_][(RH)*2+n_], 0, 0, 0);         \
    }                                                                       \
  __builtin_amdgcn_s_setprio(0);

template<int MODE>
__global__ __launch_bounds__(512, 2) void ffn_8ph_kernel(
    const f16* __restrict__ Asrc, const f16* __restrict__ Bsrc,
    const float* __restrict__ bias0, const float* __restrict__ bias1,
    const int* __restrict__ offsets, const int* __restrict__ perm,
    const float* __restrict__ gatew, f16* __restrict__ dst) {
  constexpr int KD = MODE ? H_HID : D_IN;
  constexpr int BROWS = MODE ? D_IN : 2 * H_HID;
  constexpr int NT = 16;

  __shared__ __align__(16) char smem[131072];

  int g = blockIdx.x;
  int xcd = g & 7;
  int mt = (g >> 3) & 31;
  int e, nt, kc;
  if constexpr (MODE == 0) {
    int panel = xcd + 8 * (g >> 8);   // [0,256)
    e = panel >> 5; nt = panel & 31; kc = 0;
  } else {
    int sp = xcd + 8 * (g >> 8);      // [0,128)
    e = sp >> 4; nt = (sp >> 2) & 3; kc = sp & 3;
  }

  int off = offsets[e];
  int cnt = offsets[e + 1] - off;
  if (mt * 256 >= cnt) return;

  int tid = threadIdx.x, lane = tid & 63, wid = tid >> 6;
  int wm = wid >> 2, wn = wid & 3;
  int l15 = lane & 15, lc0 = lane >> 4, s7 = l15 & 7;
  int aoff = (wm * 128 + l15) * 128;
  int boff = (wn * 64 + l15) * 128;
  int offk0 = ((lc0) ^ s7) * 16;
  int offk1 = ((lc0 + 4) ^ s7) * 16;

  int rowh_[2], lc_[2];
#pragma unroll
  for (int i = 0; i < 2; ++i) {
    int chunk = (i * 8 + wid) * 64 + lane;
    rowh_[i] = chunk >> 3;
    lc_[i] = (chunk & 7) ^ (rowh_[i] & 7);
  }

  const f16 *aB[4], *bB[4];
#pragma unroll
  for (int h = 0; h < 2; ++h)
#pragma unroll
    for (int i = 0; i < 2; ++i) {
      int absrow = h * 128 + rowh_[i];
      bB[h * 2 + i] = Bsrc + ((size_t)e * BROWS + nt * 256 + absrow) * KD +
                      kc * 1024 + lc_[i] * 8;
      int slot = off + min(mt * 256 + absrow, cnt - 1);
      if constexpr (MODE == 0)
        aB[h * 2 + i] = Asrc + (size_t)perm[slot] * KD + lc_[i] * 8;
      else
        aB[h * 2 + i] = Asrc + (size_t)slot * KD + kc * 1024 + lc_[i] * 8;
    }

  float bv0[4], bv1[2];
  if constexpr (MODE == 0) {
#pragma unroll
    for (int p = 0; p < 2; ++p) {
      int h = nt * 128 + wn * 32 + p * 16 + l15;
      bv0[p] = bias0[e * H_HID + h];
      bv1[p] = bias1[e * H_HID + h];
    }
  } else {
#pragma unroll
    for (int n = 0; n < 4; ++n)
      bv0[n] = (kc == 0)
                   ? bias0[e * D_IN + nt * 256 + wn * 64 + n * 16 + l15]
                   : 0.f;
  }

  f32x4 acc[8][4] = {};
  f16x8 fa[4][2], fb01[2][2], fb23[2][2];

  // prologue: buf0.B, buf0.A (t0); buf1.B (t1); buf1.A-H0 (t1) — 14 loads.
  STAGE_(0, 1, 0, 0, bB); STAGE_(0, 1, 1, 0, bB);
  STAGE_(0, 0, 0, 0, aB); STAGE_(0, 0, 1, 0, aB);
  STAGE_(1, 1, 0, 1, bB); STAGE_(1, 1, 1, 1, bB);
  STAGE_(1, 0, 0, 1, aB);
  VMCNT(6);
  BAR;

  for (int it = 0; it < NT / 2; ++it) {
    int b_ = 2 * it + 1;
    int a2 = min(2 * it + 2, NT - 1);
    int b2 = min(2 * it + 3, NT - 1);
    // P1
    LDA_(0, 0); LDB_(fb01, 0, 0); STAGE_(1, 0, 1, b_, aB);
    BAR; QUAD_(0, 0, fb01); BAR;
    // P2
    LDB_(fb23, 0, 1);
    BAR; QUAD_(0, 1, fb23); BAR;
    // P3
    LDA_(0, 1); STAGE_(0, 1, 0, a2, bB);
    BAR; QUAD_(1, 0, fb01); BAR;
    // P4
    STAGE_(0, 1, 1, a2, bB);
    BAR; QUAD_(1, 1, fb23);
    VMCNT(4);
    BAR;
    // P5
    LDA_(1, 0); LDB_(fb01, 1, 0); STAGE_(0, 0, 0, a2, aB);
    BAR; QUAD_(0, 0, fb01); BAR;
    // P6
    LDB_(fb23, 1, 1); STAGE_(0, 0, 1, a2, aB);
    BAR; QUAD_(0, 1, fb23); BAR;
    // P7
    LDA_(1, 1); STAGE_(1, 1, 0, b2, bB);
    BAR; QUAD_(1, 0, fb01); BAR;
    // P8
    STAGE_(1, 1, 1, b2, bB); STAGE_(1, 0, 0, b2, aB);
    BAR; QUAD_(1, 1, fb23);
    VMCNT(6);
    BAR;
  }

  // drain ALL staging loads before reusing LDS for the repack tile
  VMCNT(0);
  __syncthreads();

  int c0_ = lc0 * 4;
  f16* tile = (f16*)smem;
  if constexpr (MODE == 0) {
    // repack: [256][128] f16 (64KB)
#pragma unroll
    for (int p = 0; p < 2; ++p) {
      int colL = wn * 32 + p * 16 + l15;
#pragma unroll
      for (int m = 0; m < 8; ++m) {
        int row = wm * 128 + m * 16 + c0_;
#pragma unroll
        for (int r = 0; r < 4; ++r) {
          float gv = acc[m][2 * p][r] + bv0[p];
          float uv = acc[m][2 * p + 1][r] + bv1[p];
          tile[(row + r) * 128 + colL] = (f16)((gv / (1.f + __expf(-gv))) * uv);
        }
      }
    }
    __syncthreads();
    f16* dbase = dst + (size_t)(off + mt * 256) * H_HID + nt * 128;
#pragma unroll
    for (int i = 0; i < 8; ++i) {
      int linear = i * 512 + tid;
      int row = linear >> 4, c16 = linear & 15;
      if (mt * 256 + row < cnt) {
        f16x8 v = *(const f16x8*)&tile[row * 128 + c16 * 8];
        __builtin_nontemporal_store(v, (f16x8*)(dbase + (size_t)row * H_HID + c16 * 8));
      }
    }
  } else {
    // repack: [256][256] f16 (128KB)
#pragma unroll
    for (int n = 0; n < 4; ++n) {
      int colL = wn * 64 + n * 16 + l15;
#pragma unroll
      for (int m = 0; m < 8; ++m) {
        int row = wm * 128 + m * 16 + c0_;
#pragma unroll
        for (int r = 0; r < 4; ++r) {
          int slot = off + min(mt * 256 + row + r, cnt - 1);
          tile[(row + r) * 256 + colL] =
              (f16)(gatew[slot] * (acc[m][n][r] + bv0[n]));
        }
      }
    }
    __syncthreads();
    f16* dstP = dst + (size_t)kc * NSLOT_PAD * D_IN;
    f16* dbase = dstP + (size_t)(off + mt * 256) * D_IN + nt * 256;
#pragma unroll
    for (int i = 0; i < 16; ++i) {
      int linear = i * 512 + tid;
      int row = linear >> 5, c16 = linear & 31;
      if (mt * 256 + row < cnt) {
        f16x8 v = *(const f16x8*)&tile[row * 256 + c16 * 8];
        __builtin_nontemporal_store(v, (f16x8*)(dbase + (size_t)row * D_IN + c16 * 8));
      }
    }
  }
}

// ------- combine: out[t] = sum over s in {s0,s1}, kc in [0,4) of partial -------
__global__ __launch_bounds__(256) void combine_kernel(
    const f16* __restrict__ ypart, const int2* __restrict__ slotAB,
    float* __restrict__ out) {
  int i = blockIdx.x * 256 + threadIdx.x;
  int t = i >> 7;
  int c8 = i & 127;
  int2 s = slotAB[t];
  float sum[8] = {0.f, 0.f, 0.f, 0.f, 0.f, 0.f, 0.f, 0.f};
#pragma unroll
  for (int kc = 0; kc < KSPLIT; ++kc) {
    const f16* base = ypart + (size_t)kc * NSLOT_PAD * D_IN + c8 * 8;
    f16x8 y0 = *(const f16x8*)(base + (size_t)s.x * D_IN);
    f16x8 y1 = *(const f16x8*)(base + (size_t)s.y * D_IN);
#pragma unroll
    for (int j = 0; j < 8; ++j) sum[j] += (float)y0[j] + (float)y1[j];
  }
  float* o = out + (size_t)t * D_IN + c8 * 8;
  f32x4 o0 = {sum[0], sum[1], sum[2], sum[3]};
  f32x4 o1 = {sum[4], sum[5], sum[6], sum[7]};
  __builtin_nontemporal_store(o0, (f32x4*)o);
  __builtin_nontemporal_store(o1, (f32x4*)(o + 4));
}

// ---------------- launch ----------------

extern "C" void kernel_launch(void* const* d_in, const int* in_sizes, int n_in,
                              void* d_out, int out_size, void* d_ws, size_t ws_size,
                              hipStream_t stream) {
  const float* x  = (const float*)d_in[0];
  const float* Wr = (const float*)d_in[1];
  const float* br = (const float*)d_in[2];
  const float* Wg = (const float*)d_in[3];
  const float* bg = (const float*)d_in[4];
  const float* Wu = (const float*)d_in[5];
  const float* bu = (const float*)d_in[6];
  const float* Wd = (const float*)d_in[7];
  const float* bd = (const float*)d_in[8];
  float* out = (float*)d_out;

  char* ws = (char*)d_ws;
  size_t o = 0;
  auto alloc = [&](size_t bytes) {
    size_t r = o;
    o += (bytes + 255) & ~(size_t)255;
    return r;
  };
  f16* xb     = (f16*)(ws + alloc((size_t)T_TOK * D_IN * 2));               // 16MB
  f16* wgut   = (f16*)(ws + alloc((size_t)E_EXP * 2 * H_HID * D_IN * 2));   // 128MB
  f16* wdt    = (f16*)(ws + alloc((size_t)E_EXP * D_IN * H_HID * 2));       // 64MB
  f16* hbuf   = (f16*)(ws + alloc((size_t)NSLOT_PAD * H_HID * 2));          // 135MB
  int* eidx   = (int*)(ws + alloc((size_t)T_TOK * 4));
  float2* pval= (float2*)(ws + alloc((size_t)T_TOK * 8));
  int* counts = (int*)(ws + alloc(64 * 4));
  int* cursors = counts + 8;
  int* offsets = counts + 16;
  int* perm   = (int*)(ws + alloc((size_t)NSLOT_PAD * 4));
  float* gatew= (float*)(ws + alloc((size_t)NSLOT_PAD * 4));
  int2* slotAB= (int2*)(ws + alloc((size_t)T_TOK * 8));
  // ypart aliases xb+wgut (both dead after ffn1): 4*34MB = 136MB <= 144MB.
  f16* ypart  = xb;

  hipMemsetAsync(counts, 0, 64 * 4, stream);

  // prep: router (2048 blocks) + Wg/Wu/Wd transposes (3 x 8192 blocks)
  prep_kernel<<<dim3(T_TOK / 4 + 3 * 8192), 256, 0, stream>>>(
      x, Wr, br, Wg, Wu, Wd, eidx, pval, counts, xb, wgut, wdt);
  scan_kernel<<<1, 64, 0, stream>>>(counts, offsets);
  scatter_kernel<<<T_TOK / 256, 256, 0, stream>>>(eidx, pval, offsets, cursors,
                                                  perm, gatew, slotAB);
  // FFN1: 8192 blocks, XCD-panel affinity.
  ffn_8ph_kernel<0><<<dim3(8192), 512, 0, stream>>>(
      xb, wgut, bg, bu, offsets, perm, nullptr, hbuf);
  // FFN2: 4096 blocks, split-K=4, disjoint f16 partials (no atomics).
  ffn_8ph_kernel<1><<<dim3(4096), 512, 0, stream>>>(
      hbuf, wdt, bd, nullptr, offsets, nullptr, gatew, ypart);
  combine_kernel<<<T_TOK * D_IN / 8 / 256, 256, 0, stream>>>(ypart, slotAB, out);
}